// Round 1
// baseline (2042.637 us; speedup 1.0000x reference)
//
#include <hip/hip_runtime.h>

// Problem constants
#define BB 2048
#define TT 26
#define DIN 512
#define HH 512
#define EE 256
#define CC 97
#define SS 32
#define G4 2048   // 4*H
#define XK2 1024  // gates GEMM K: ctx(512) + h(512); ce folded into P lookup

typedef unsigned short u16;
typedef __bf16 bf16x8 __attribute__((ext_vector_type(8)));
typedef float f32x4 __attribute__((ext_vector_type(4)));

__device__ __forceinline__ float bf2f(u16 u) {
    return __uint_as_float(((unsigned int)u) << 16);
}
__device__ __forceinline__ u16 f2bf(float f) {  // RNE
    unsigned int u = __float_as_uint(f);
    u = u + 0x7FFFu + ((u >> 16) & 1u);
    return (u16)(u >> 16);
}
__device__ __forceinline__ float th_f(float x) {
    return 1.0f - 2.0f * __builtin_amdgcn_rcpf(__expf(2.0f * x) + 1.0f);
}
__device__ __forceinline__ float sig_f(float x) {
    return __builtin_amdgcn_rcpf(1.0f + __expf(-x));
}

// async global->LDS, 16B/lane; LDS base wave-uniform
__device__ __forceinline__ void async16(const u16* g, u16* l) {
    __builtin_amdgcn_global_load_lds(
        (const __attribute__((address_space(1))) unsigned int*)(g),
        (__attribute__((address_space(3))) unsigned int*)(l), 16, 0, 0);
}

// ---------------------------------------------------------------------------
// gemm128 (Hp): C[M,N] = A[M,K] @ W[N,K]^T, 128x128 tile, m97 staging, bf16 out
// ---------------------------------------------------------------------------
__global__ __launch_bounds__(256) void gemm128(
    const u16* __restrict__ A, int lda,
    const u16* __restrict__ W,
    u16* __restrict__ Cout, int ldc, int K)
{
    __shared__ __align__(16) u16 As[128 * 32];
    __shared__ __align__(16) u16 Ws[128 * 32];

    const int tid  = threadIdx.x;
    const int lane = tid & 63;
    const int wave = tid >> 6;
    const int m0 = blockIdx.y * 128;
    const int n0 = blockIdx.x * 128;

    const int srow = tid >> 2;
    const int scol = (tid & 3) * 8;
    const u16* Arow0 = A + (size_t)(m0 + srow) * lda + scol;
    const u16* Arow1 = A + (size_t)(m0 + 64 + srow) * lda + scol;
    const u16* Wrow0 = W + (size_t)(n0 + srow) * K + scol;
    const u16* Wrow1 = W + (size_t)(n0 + 64 + srow) * K + scol;
    u16* dstA0 = As + wave * 512;
    u16* dstA1 = As + 2048 + wave * 512;
    u16* dstW0 = Ws + wave * 512;
    u16* dstW1 = Ws + 2048 + wave * 512;

    const int wm = (wave >> 1) * 64;
    const int wn = (wave & 1) * 64;
    const int fr = lane & 15;
    const int fq = lane >> 4;

    f32x4 acc[4][4];
    #pragma unroll
    for (int i = 0; i < 4; i++)
        #pragma unroll
        for (int j = 0; j < 4; j++)
            #pragma unroll
            for (int r = 0; r < 4; r++) acc[i][j][r] = 0.0f;

    for (int k0 = 0; k0 < K; k0 += 32) {
        async16(Arow0 + k0, dstA0);
        async16(Arow1 + k0, dstA1);
        async16(Wrow0 + k0, dstW0);
        async16(Wrow1 + k0, dstW1);
        __syncthreads();
        bf16x8 af[4], bw[4];
        #pragma unroll
        for (int i = 0; i < 4; i++)
            af[i] = *(const bf16x8*)&As[(wm + i * 16 + fr) * 32 + fq * 8];
        #pragma unroll
        for (int j = 0; j < 4; j++)
            bw[j] = *(const bf16x8*)&Ws[(wn + j * 16 + fr) * 32 + fq * 8];
        #pragma unroll
        for (int i = 0; i < 4; i++)
            #pragma unroll
            for (int j = 0; j < 4; j++)
                acc[i][j] = __builtin_amdgcn_mfma_f32_16x16x32_bf16(
                    af[i], bw[j], acc[i][j], 0, 0, 0);
        __syncthreads();
    }

    #pragma unroll
    for (int j = 0; j < 4; j++) {
        int col = n0 + wn + j * 16 + fr;
        #pragma unroll
        for (int i = 0; i < 4; i++) {
            int row = m0 + wm + i * 16 + fq * 4;
            #pragma unroll
            for (int r = 0; r < 4; r++)
                Cout[(size_t)(row + r) * ldc + col] = f2bf(acc[i][j][r]);
        }
    }
}

// ---------------------------------------------------------------------------
// gen128: probs = hid[1..32] @ Wgen^T + b_gen.  M=65536 (s-major rows),
// N=128 (97 valid), K=512.  grid (1, 512).  out[b][s][c] scatter on store.
// ---------------------------------------------------------------------------
__global__ __launch_bounds__(256) void gen128(
    const u16* __restrict__ A,        // hid + B*H, rows stride 512
    const u16* __restrict__ Wg,       // [128][512] padded
    const float* __restrict__ bgen,   // [97] fp32
    float* __restrict__ out)
{
    __shared__ __align__(16) u16 As[128 * 32];
    __shared__ __align__(16) u16 Ws[128 * 32];

    const int tid  = threadIdx.x;
    const int lane = tid & 63;
    const int wave = tid >> 6;
    const int m0 = blockIdx.y * 128;

    const int srow = tid >> 2;
    const int scol = (tid & 3) * 8;
    const u16* Arow0 = A + (size_t)(m0 + srow) * HH + scol;
    const u16* Arow1 = A + (size_t)(m0 + 64 + srow) * HH + scol;
    const u16* Wrow0 = Wg + (size_t)srow * HH + scol;
    const u16* Wrow1 = Wg + (size_t)(64 + srow) * HH + scol;
    u16* dstA0 = As + wave * 512;
    u16* dstA1 = As + 2048 + wave * 512;
    u16* dstW0 = Ws + wave * 512;
    u16* dstW1 = Ws + 2048 + wave * 512;

    const int wm = (wave >> 1) * 64;
    const int wn = (wave & 1) * 64;
    const int fr = lane & 15;
    const int fq = lane >> 4;

    f32x4 acc[4][4];
    #pragma unroll
    for (int i = 0; i < 4; i++)
        #pragma unroll
        for (int j = 0; j < 4; j++)
            #pragma unroll
            for (int r = 0; r < 4; r++) acc[i][j][r] = 0.0f;

    for (int k0 = 0; k0 < HH; k0 += 32) {
        async16(Arow0 + k0, dstA0);
        async16(Arow1 + k0, dstA1);
        async16(Wrow0 + k0, dstW0);
        async16(Wrow1 + k0, dstW1);
        __syncthreads();
        bf16x8 af[4], bw[4];
        #pragma unroll
        for (int i = 0; i < 4; i++)
            af[i] = *(const bf16x8*)&As[(wm + i * 16 + fr) * 32 + fq * 8];
        #pragma unroll
        for (int j = 0; j < 4; j++)
            bw[j] = *(const bf16x8*)&Ws[(wn + j * 16 + fr) * 32 + fq * 8];
        #pragma unroll
        for (int i = 0; i < 4; i++)
            #pragma unroll
            for (int j = 0; j < 4; j++)
                acc[i][j] = __builtin_amdgcn_mfma_f32_16x16x32_bf16(
                    af[i], bw[j], acc[i][j], 0, 0, 0);
        __syncthreads();
    }

    #pragma unroll
    for (int j = 0; j < 4; j++) {
        int col = wn + j * 16 + fr;
        if (col < CC) {
            float bv = bgen[col];
            #pragma unroll
            for (int i = 0; i < 4; i++) {
                int row = m0 + wm + i * 16 + fq * 4;
                #pragma unroll
                for (int r = 0; r < 4; r++) {
                    int m = row + r;
                    int s = m >> 11, b = m & (BB - 1);
                    out[(size_t)b * (SS * CC) + s * CC + col] = acc[i][j][r] + bv;
                }
            }
        }
    }
}

// ---------------------------------------------------------------------------
// gates_lstm: gates = [ctx|h_s] @ Wcat^T (interleaved col=4h+g), epilogue adds
// bcat + P[char] and applies LSTM.  Tile 64(M)x128(N), grid (16,32)=512.
// h_{s+1} -> hnext (s-major hid buffer).
// ---------------------------------------------------------------------------
__global__ __launch_bounds__(256) void gates_lstm(
    const u16* __restrict__ ctx,    // [B][512]
    const u16* __restrict__ hprev,  // [B][512] (hid slot s)
    const u16* __restrict__ Wc,     // [2048][1024] interleaved
    const float* __restrict__ bcat, // [2048] interleaved
    const float* __restrict__ P,    // [128][2048] char-gate bias, interleaved
    const int* __restrict__ text,   // [B][SS]
    float* __restrict__ c,          // [B][512]
    u16* __restrict__ hnext,        // [B][512] (hid slot s+1)
    int s)
{
    __shared__ __align__(16) u16 As[64 * 32];    // 4 KB
    __shared__ __align__(16) u16 Ws[128 * 32];   // 8 KB
    __shared__ float gsm[64 * 68];               // 17 KB
    __shared__ int text_sm[64];

    const int tid  = threadIdx.x;
    const int lane = tid & 63;
    const int wave = tid >> 6;

    // XCD swizzle: per-XCD 8x8 region (A 8 strips + W 8 strips < 4 MB L2)
    int b   = blockIdx.y * gridDim.x + blockIdx.x;
    int xcd = b & 7, loc = b >> 3;
    int by = (xcd & 3) * 8 + (loc & 7);     // 0..31  (M tiles)
    int bx = (xcd >> 2) * 8 + (loc >> 3);   // 0..15  (N tiles)
    const int m0 = by * 64;
    const int n0 = bx * 128;

    if (tid < 64) text_sm[tid] = text[(m0 + tid) * SS + s];

    const int srow = tid >> 2;
    const int scol = (tid & 3) * 8;
    const u16* Actx  = ctx   + (size_t)(m0 + srow) * 512 + scol;
    const u16* Ahid  = hprev + (size_t)(m0 + srow) * 512 + scol;
    const u16* Wrow0 = Wc + (size_t)(n0 + srow) * XK2 + scol;
    const u16* Wrow1 = Wc + (size_t)(n0 + 64 + srow) * XK2 + scol;
    u16* dstA  = As + wave * 512;
    u16* dstW0 = Ws + wave * 512;
    u16* dstW1 = Ws + 2048 + wave * 512;

    const int wm = (wave & 1) * 32;   // 2x2 wave grid: 32M x 64N each
    const int wn = (wave >> 1) * 64;
    const int fr = lane & 15;
    const int fq = lane >> 4;

    f32x4 acc[2][4];
    #pragma unroll
    for (int i = 0; i < 2; i++)
        #pragma unroll
        for (int j = 0; j < 4; j++)
            #pragma unroll
            for (int r = 0; r < 4; r++) acc[i][j][r] = 0.0f;

    #pragma unroll
    for (int k0 = 0; k0 < XK2; k0 += 32) {
        const u16* asrc = (k0 < 512) ? (Actx + k0) : (Ahid + (k0 - 512));
        async16(asrc, dstA);
        async16(Wrow0 + k0, dstW0);
        async16(Wrow1 + k0, dstW1);
        __syncthreads();
        bf16x8 af[2], bw[4];
        #pragma unroll
        for (int i = 0; i < 2; i++)
            af[i] = *(const bf16x8*)&As[(wm + i * 16 + fr) * 32 + fq * 8];
        #pragma unroll
        for (int j = 0; j < 4; j++)
            bw[j] = *(const bf16x8*)&Ws[(wn + j * 16 + fr) * 32 + fq * 8];
        #pragma unroll
        for (int i = 0; i < 2; i++)
            #pragma unroll
            for (int j = 0; j < 4; j++)
                acc[i][j] = __builtin_amdgcn_mfma_f32_16x16x32_bf16(
                    af[i], bw[j], acc[i][j], 0, 0, 0);
        __syncthreads();
    }

    // Epilogue: two 64-col passes -> LDS, then fused LSTM (bias+P added here)
    #pragma unroll
    for (int p = 0; p < 2; p++) {
        if ((wave >> 1) == p) {
            #pragma unroll
            for (int j = 0; j < 4; j++) {
                int cl = j * 16 + fr;
                #pragma unroll
                for (int i = 0; i < 2; i++) {
                    int rl = wm + i * 16 + fq * 4;
                    #pragma unroll
                    for (int r = 0; r < 4; r++)
                        gsm[(rl + r) * 68 + cl] = acc[i][j][r];
                }
            }
        }
        __syncthreads();
        #pragma unroll
        for (int rr = 0; rr < 4; rr++) {
            int idx = rr * 256 + tid;
            int u = idx & 15, row = idx >> 4;
            int base = row * 68 + 4 * u;
            int hg = (n0 >> 2) + p * 16 + u;   // global h unit
            int c0 = 4 * hg;                    // interleaved gate col base
            int ch = text_sm[row];
            float4 bc = *(const float4*)(bcat + c0);
            float4 pv = *(const float4*)(P + (size_t)ch * G4 + c0);
            float ig = sig_f(gsm[base]     + bc.x + pv.x);
            float fg = sig_f(gsm[base + 1] + bc.y + pv.y);
            float gg = th_f (gsm[base + 2] + bc.z + pv.z);
            float og = sig_f(gsm[base + 3] + bc.w + pv.w);
            size_t ci = (size_t)(m0 + row) * HH + hg;
            float cn = fg * c[ci] + ig * gg;
            c[ci] = cn;
            hnext[(size_t)(m0 + row) * HH + hg] = f2bf(og * th_f(cn));
        }
        __syncthreads();
    }
}

// ---------------------------------------------------------------------------
// gemm64: 64x64-tile GEMM, fp32 out + bias. Used for the one-time P build
// (N=2048,K=256).
// ---------------------------------------------------------------------------
__global__ __launch_bounds__(256) void gemm64(
    const u16* __restrict__ A, int lda,
    const u16* __restrict__ W, int ldw,
    const float* __restrict__ bias,
    float* __restrict__ Cout, int ldc, int K, int use_bias)
{
    __shared__ __align__(16) u16 As[64][32];
    __shared__ __align__(16) u16 Ws[64][32];

    const int tid  = threadIdx.x;
    const int lane = tid & 63;
    const int wave = tid >> 6;
    const int m0 = blockIdx.y * 64;
    const int n0 = blockIdx.x * 64;
    const int ar = tid >> 2;
    const int ac = (tid & 3) * 8;
    const int wm = (wave >> 1) * 32;
    const int wn = (wave & 1) * 32;
    const int fr = lane & 15;
    const int fq = lane >> 4;

    f32x4 acc[2][2];
    #pragma unroll
    for (int i = 0; i < 2; i++)
        #pragma unroll
        for (int j = 0; j < 2; j++)
            #pragma unroll
            for (int r = 0; r < 4; r++) acc[i][j][r] = 0.0f;

    const u16* Arow = A + (size_t)(m0 + ar) * lda;
    const u16* Wrow = W + (size_t)(n0 + ar) * ldw;

    for (int k0 = 0; k0 < K; k0 += 32) {
        *(uint4*)&As[ar][ac] = *(const uint4*)(Arow + k0 + ac);
        *(uint4*)&Ws[ar][ac] = *(const uint4*)(Wrow + k0 + ac);
        __syncthreads();
        bf16x8 af[2], bw[2];
        #pragma unroll
        for (int mm = 0; mm < 2; mm++)
            af[mm] = *(const bf16x8*)&As[wm + mm * 16 + fr][fq * 8];
        #pragma unroll
        for (int nn = 0; nn < 2; nn++)
            bw[nn] = *(const bf16x8*)&Ws[wn + nn * 16 + fr][fq * 8];
        #pragma unroll
        for (int mm = 0; mm < 2; mm++)
            #pragma unroll
            for (int nn = 0; nn < 2; nn++)
                acc[mm][nn] = __builtin_amdgcn_mfma_f32_16x16x32_bf16(
                    af[mm], bw[nn], acc[mm][nn], 0, 0, 0);
        __syncthreads();
    }

    #pragma unroll
    for (int nn = 0; nn < 2; nn++) {
        int col = n0 + wn + nn * 16 + fr;
        float bv = use_bias ? bias[col] : 0.0f;
        #pragma unroll
        for (int mm = 0; mm < 2; mm++) {
            int row = m0 + wm + mm * 16 + fq * 4;
            #pragma unroll
            for (int r = 0; r < 4; r++)
                Cout[(size_t)(row + r) * ldc + col] = acc[mm][nn][r] + bv;
        }
    }
}

// ---------------------------------------------------------------------------
// attnph: fused ph-GEMM + attention.  512 threads (8 waves), 8 batch rows per
// block, grid 256.
//   Phase A: ph[8][512] = hprev[8r] @ W_h2h^T + b_h2h (16x16x32 MFMA, M=16
//            with rows 8..15 zero-padded; W pre-swizzled into frag order so
//            every W load is a coalesced 1KB wave read; A-tile XOR-swizzled
//            in LDS to kill the 16-way ds_read_b128 bank conflict).
//   Phase B: e[t] = sum_h tanh(Hp+ph)*ws  (one row per wave, 16B/lane loads,
//            wave-parallel softmax -- no serial tid==0 section).
//   Phase C: ctx = alpha @ batch_H        (16B/lane, one row per wave).
// ---------------------------------------------------------------------------
__global__ __launch_bounds__(512) void attnph(
    const u16* __restrict__ hprev,   // [B][512] bf16 (hid slot s; slot0 = 0)
    const u16* __restrict__ Wsw,     // [512*512] swizzled W_h2h frags
    const float* __restrict__ bh2h,  // [512] f32
    const u16* __restrict__ Hp,      // [B*T][512] bf16
    const u16* __restrict__ bH16,    // [B*T][512] bf16
    const float* __restrict__ wscore,// [512] f32
    u16* __restrict__ ctx)           // [B][512] bf16 out
{
    __shared__ __align__(16) u16 As[16 * 512];      // 16 KB (XOR-swizzled)
    __shared__ __align__(16) float phs[8 * 512];    // 16 KB
    __shared__ float e_sm[8][28];
    __shared__ float alpha_sm[8][28];

    const int tid  = threadIdx.x;
    const int lane = tid & 63;
    const int wave = tid >> 6;      // 0..7
    const int m0   = blockIdx.x * 8;
    const int fr   = lane & 15;
    const int fq   = lane >> 4;

    // stage hprev rows 0..7 into As (swizzled), zero rows 8..15
    {
        int row = tid >> 6;          // 0..7
        int c0  = (tid & 63) * 8;    // elem offset, 16B per thread
        int sw  = (row & 7) << 4;
        int b1  = (row * 1024 + c0 * 2) ^ sw;
        int b2  = ((row + 8) * 1024 + c0 * 2) ^ sw;
        *(uint4*)((char*)As + b1) =
            *(const uint4*)(hprev + (size_t)(m0 + row) * 512 + c0);
        uint4 z = make_uint4(0u, 0u, 0u, 0u);
        *(uint4*)((char*)As + b2) = z;
    }
    __syncthreads();

    // Phase A: wave w computes ph cols w*64 .. w*64+63
    f32x4 acc[4];
    #pragma unroll
    for (int j = 0; j < 4; j++)
        #pragma unroll
        for (int r = 0; r < 4; r++) acc[j][r] = 0.0f;

    #pragma unroll
    for (int kk = 0; kk < 16; kk++) {
        int rb = (fr * 1024 + kk * 64 + fq * 16) ^ ((fr & 7) << 4);
        bf16x8 af = *(const bf16x8*)((const char*)As + rb);
        #pragma unroll
        for (int j = 0; j < 4; j++) {
            int jj = wave * 4 + j;   // global n-tile
            bf16x8 wv = *(const bf16x8*)&Wsw[((size_t)(jj * 16 + kk) * 64 + lane) * 8];
            acc[j] = __builtin_amdgcn_mfma_f32_16x16x32_bf16(af, wv, acc[j], 0, 0, 0);
        }
    }
    // C layout: col = fr (n within tile), row = fq*4 + r (batch row; keep < 8)
    if (fq < 2) {
        #pragma unroll
        for (int j = 0; j < 4; j++) {
            int n = wave * 64 + j * 16 + fr;
            float bv = bh2h[n];
            #pragma unroll
            for (int r = 0; r < 4; r++)
                phs[(fq * 4 + r) * 512 + n] = acc[j][r] + bv;
        }
    }
    __syncthreads();

    // Phase B: one row per wave
    const int row = wave;
    const int h8  = lane * 8;
    float ws_r[8], ph_r[8];
    {
        float4 w0 = *(const float4*)(wscore + h8);
        float4 w1 = *(const float4*)(wscore + h8 + 4);
        ws_r[0]=w0.x; ws_r[1]=w0.y; ws_r[2]=w0.z; ws_r[3]=w0.w;
        ws_r[4]=w1.x; ws_r[5]=w1.y; ws_r[6]=w1.z; ws_r[7]=w1.w;
        float4 p0 = *(const float4*)&phs[row * 512 + h8];
        float4 p1 = *(const float4*)&phs[row * 512 + h8 + 4];
        ph_r[0]=p0.x; ph_r[1]=p0.y; ph_r[2]=p0.z; ph_r[3]=p0.w;
        ph_r[4]=p1.x; ph_r[5]=p1.y; ph_r[6]=p1.z; ph_r[7]=p1.w;
    }
    {
        const u16* hpb = Hp + (size_t)(m0 + row) * TT * 512 + h8;
        for (int t = 0; t < TT; t++) {
            uint4 hv = *(const uint4*)(hpb + (size_t)t * 512);
            const u16* hu = (const u16*)&hv;
            float sum = 0.0f;
            #pragma unroll
            for (int j = 0; j < 8; j++)
                sum += th_f(bf2f(hu[j]) + ph_r[j]) * ws_r[j];
            #pragma unroll
            for (int off = 32; off > 0; off >>= 1) sum += __shfl_down(sum, off);
            if (lane == 0) e_sm[row][t] = sum;
        }
    }
    __syncthreads();

    // wave-parallel softmax over t
    {
        float ev = (lane < TT) ? e_sm[row][lane] : -3.0e38f;
        float mx = ev;
        #pragma unroll
        for (int off = 32; off > 0; off >>= 1)
            mx = fmaxf(mx, __shfl_xor(mx, off));
        float p = (lane < TT) ? __expf(ev - mx) : 0.0f;
        float ssum = p;
        #pragma unroll
        for (int off = 32; off > 0; off >>= 1) ssum += __shfl_xor(ssum, off);
        if (lane < TT) alpha_sm[row][lane] = p / ssum;
    }
    __syncthreads();

    // Phase C: context = alpha @ batch_H, one row per wave, 16B/lane
    {
        float ca[8];
        #pragma unroll
        for (int j = 0; j < 8; j++) ca[j] = 0.0f;
        const u16* bb = bH16 + (size_t)(m0 + row) * TT * 512 + h8;
        #pragma unroll
        for (int t = 0; t < TT; t++) {
            uint4 v = *(const uint4*)(bb + (size_t)t * 512);
            const u16* vu = (const u16*)&v;
            float a = alpha_sm[row][t];
            #pragma unroll
            for (int j = 0; j < 8; j++) ca[j] += a * bf2f(vu[j]);
        }
        u16 o[8];
        #pragma unroll
        for (int j = 0; j < 8; j++) o[j] = f2bf(ca[j]);
        *(uint4*)(ctx + (size_t)(m0 + row) * 512 + h8) = *(const uint4*)o;
    }
}

// ---------------------------------------------------------------------------
// prep: bH16 cast (separate, big) + prep_all (everything else, one launch)
// ---------------------------------------------------------------------------
__global__ __launch_bounds__(256) void cast_f32_bf16(
    const float* __restrict__ src, u16* __restrict__ dst, int n)
{
    int i = (blockIdx.x * 256 + threadIdx.x) * 4;
    if (i < n) {
        float4 v = *(const float4*)(src + i);
        ushort4 o;
        o.x = f2bf(v.x); o.y = f2bf(v.y); o.z = f2bf(v.z); o.w = f2bf(v.w);
        *(ushort4*)(dst + i) = o;
    }
}

__global__ __launch_bounds__(256) void prep_all(
    const float* __restrict__ W_ih, const float* __restrict__ W_hh,
    const float* __restrict__ b_ih, const float* __restrict__ b_hh,
    const float* __restrict__ emb,
    const float* __restrict__ W_i2h, const float* __restrict__ W_h2h,
    const float* __restrict__ W_gen,
    u16* __restrict__ Wcat, u16* __restrict__ Wce16, u16* __restrict__ emb16,
    u16* __restrict__ Wgen16, u16* __restrict__ Wi2h16, u16* __restrict__ Wsw,
    float* __restrict__ bcat, float* __restrict__ cst, u16* __restrict__ hid0)
{
    int i = blockIdx.x * 256 + threadIdx.x;   // grid covers 2,097,152

    // Wcat [2048][1024] interleaved row np=4h+g: [W_ih[:, :512] | W_hh]
    {
        int np = i >> 10, k = i & (XK2 - 1);
        int h = np >> 2, g = np & 3;
        int n = g * HH + h;
        float v = (k < 512) ? W_ih[(size_t)n * (DIN + EE) + k]
                            : W_hh[(size_t)n * HH + (k - 512)];
        Wcat[(size_t)i] = f2bf(v);
    }
    // Wce16 [2048][256] interleaved: W_ih[:, 512:768]
    if (i < G4 * EE) {
        int np = i >> 8, e = i & (EE - 1);
        int h = np >> 2, g = np & 3;
        int n = g * HH + h;
        Wce16[i] = f2bf(W_ih[(size_t)n * (DIN + EE) + DIN + e]);
    }
    // emb16 [128][256], rows >= 97 zeroed
    if (i < 128 * EE) {
        int ch = i >> 8, e = i & (EE - 1);
        emb16[i] = (ch < CC) ? f2bf(emb[(size_t)ch * EE + e]) : (u16)0;
    }
    // Wgen16 [128][512], rows >= 97 zeroed
    if (i < 128 * HH) {
        int n = i >> 9, k = i & (HH - 1);
        Wgen16[i] = (n < CC) ? f2bf(W_gen[(size_t)n * HH + k]) : (u16)0;
    }
    // Wi2h16 plain cast
    if (i < HH * DIN) Wi2h16[i] = f2bf(W_i2h[i]);
    // Wsw: W_h2h swizzled into MFMA-frag order.
    // Wsw[((jj*16+kk)*64 + l)*8 + e] = W_h2h[jj*16 + (l&15)][kk*32 + (l>>4)*8 + e]
    if (i < HH * HH) {
        int e = i & 7, l = (i >> 3) & 63, kk = (i >> 9) & 15, jj = i >> 13;
        int rrow = jj * 16 + (l & 15);
        int rcol = kk * 32 + (l >> 4) * 8 + e;
        Wsw[i] = f2bf(W_h2h[(size_t)rrow * HH + rcol]);
    }
    // bcat interleaved
    if (i < G4) {
        int h = i >> 2, g = i & 3;
        int n = g * HH + h;
        bcat[i] = b_ih[n] + b_hh[n];
    }
    // state init: c=0, hid slot0 = 0 (so step-0 ph = b_h2h inside attnph)
    if (i < BB * HH) {
        cst[i] = 0.0f;
        hid0[i] = 0;
    }
}

// ---------------------------------------------------------------------------
// Workspace layout (bytes)
// ---------------------------------------------------------------------------
#define BH16_OFF  ((size_t)0)             // bf16 [B*T, DIN]   54,525,952
#define HP_OFF    ((size_t)54525952)      // bf16 [B*T, H]     54,525,952
#define HID_OFF   ((size_t)109051904)     // bf16 [33][B][H]   69,206,016
#define CTX_OFF   ((size_t)178257920)     // bf16 [B][512]      2,097,152
#define WCAT_OFF  ((size_t)180355072)     // bf16 [2048][1024]  4,194,304
#define WCE_OFF   ((size_t)184549376)     // bf16 [2048][256]   1,048,576
#define EMB16_OFF ((size_t)185597952)     // bf16 [128][256]       65,536
#define WGEN_OFF  ((size_t)185663488)     // bf16 [128][512]      131,072
#define WI2H_OFF  ((size_t)185794560)     // bf16 [512][512]      524,288
#define WSW_OFF   ((size_t)186318848)     // bf16 [512][512] swizzled 524,288
#define BCAT_OFF  ((size_t)186843136)     // f32 [2048]             8,192
#define P_OFF     ((size_t)186851328)     // f32 [128][2048]    1,048,576
#define CST_OFF   ((size_t)192094208)     // f32 [B][512]       4,194,304

extern "C" void kernel_launch(void* const* d_in, const int* in_sizes, int n_in,
                              void* d_out, int out_size, void* d_ws, size_t ws_size,
                              hipStream_t stream)
{
    const float* batch_H = (const float*)d_in[0];
    const int*   text    = (const int*)d_in[1];
    const float* W_i2h   = (const float*)d_in[2];
    const float* W_h2h   = (const float*)d_in[3];
    const float* b_h2h   = (const float*)d_in[4];
    const float* w_score = (const float*)d_in[5];
    const float* W_ih    = (const float*)d_in[6];
    const float* W_hh    = (const float*)d_in[7];
    const float* b_ih    = (const float*)d_in[8];
    const float* b_hh    = (const float*)d_in[9];
    const float* W_gen   = (const float*)d_in[10];
    const float* b_gen   = (const float*)d_in[11];
    const float* emb     = (const float*)d_in[12];

    char* ws = (char*)d_ws;
    u16*   bH16   = (u16*)(ws + BH16_OFF);
    u16*   Hp     = (u16*)(ws + HP_OFF);
    u16*   hid    = (u16*)(ws + HID_OFF);
    u16*   ctx    = (u16*)(ws + CTX_OFF);
    u16*   Wcat   = (u16*)(ws + WCAT_OFF);
    u16*   Wce16  = (u16*)(ws + WCE_OFF);
    u16*   emb16  = (u16*)(ws + EMB16_OFF);
    u16*   Wgen16 = (u16*)(ws + WGEN_OFF);
    u16*   Wi2h16 = (u16*)(ws + WI2H_OFF);
    u16*   Wsw    = (u16*)(ws + WSW_OFF);
    float* bcat   = (float*)(ws + BCAT_OFF);
    float* P      = (float*)(ws + P_OFF);
    float* cst    = (float*)(ws + CST_OFF);
    float* out    = (float*)d_out;

    // prep (3 launches)
    cast_f32_bf16<<<dim3((BB * TT * DIN / 4 + 255) / 256), 256, 0, stream>>>(
        batch_H, bH16, BB * TT * DIN);
    prep_all<<<dim3((G4 * XK2) / 256), 256, 0, stream>>>(
        W_ih, W_hh, b_ih, b_hh, emb, W_i2h, W_h2h, W_gen,
        Wcat, Wce16, emb16, Wgen16, Wi2h16, Wsw, bcat, cst, hid);
    // P[128][2048] = emb16 @ Wce16^T  (fp32 out)
    gemm64<<<dim3(G4 / 64, 128 / 64), 256, 0, stream>>>(
        emb16, EE, Wce16, EE, nullptr, P, G4, EE, 0);

    // Hp = batch_H @ W_i2h^T
    gemm128<<<dim3(HH / 128, (BB * TT) / 128), 256, 0, stream>>>(
        bH16, DIN, Wi2h16, Hp, HH, DIN);

    for (int s = 0; s < SS; s++) {
        u16* hprev = hid + (size_t)s * BB * HH;
        u16* hnext = hid + (size_t)(s + 1) * BB * HH;

        // fused ph-GEMM + attention -> ctx
        attnph<<<dim3(BB / 8), 512, 0, stream>>>(
            hprev, Wsw, b_h2h, Hp, bH16, w_score, ctx);

        gates_lstm<<<dim3(G4 / 128, BB / 64), 256, 0, stream>>>(
            ctx, hprev, Wcat, bcat, P, text, cst, hnext, s);
    }

    // probs = hid[1..32] @ W_gen^T + b_gen  (one big GEMM, scatter store)
    gen128<<<dim3(1, (SS * BB) / 128), 256, 0, stream>>>(
        hid + (size_t)BB * HH, Wgen16, b_gen, out);
}

// Round 2
// 1804.747 us; speedup vs baseline: 1.1318x; 1.1318x over previous
//
#include <hip/hip_runtime.h>

// Problem constants
#define BB 2048
#define TT 26
#define DIN 512
#define HH 512
#define EE 256
#define CC 97
#define SS 32
#define G4 2048   // 4*H
#define XK2 1024  // gates GEMM K: ctx(512) + h(512); ce folded into P lookup

typedef unsigned short u16;
typedef __bf16 bf16x8 __attribute__((ext_vector_type(8)));
typedef float f32x4 __attribute__((ext_vector_type(4)));

__device__ __forceinline__ float bf2f(u16 u) {
    return __uint_as_float(((unsigned int)u) << 16);
}
__device__ __forceinline__ u16 f2bf(float f) {  // RNE
    unsigned int u = __float_as_uint(f);
    u = u + 0x7FFFu + ((u >> 16) & 1u);
    return (u16)(u >> 16);
}
__device__ __forceinline__ float th_f(float x) {
    return 1.0f - 2.0f * __builtin_amdgcn_rcpf(__expf(2.0f * x) + 1.0f);
}
__device__ __forceinline__ float sig_f(float x) {
    return __builtin_amdgcn_rcpf(1.0f + __expf(-x));
}

// async global->LDS, 16B/lane; LDS base wave-uniform
__device__ __forceinline__ void async16(const u16* g, u16* l) {
    __builtin_amdgcn_global_load_lds(
        (const __attribute__((address_space(1))) unsigned int*)(g),
        (__attribute__((address_space(3))) unsigned int*)(l), 16, 0, 0);
}

// ---------------------------------------------------------------------------
// gemm128 (Hp): C[M,N] = A[M,K] @ W[N,K]^T, 128x128 tile, m97 staging, bf16 out
// ---------------------------------------------------------------------------
__global__ __launch_bounds__(256) void gemm128(
    const u16* __restrict__ A, int lda,
    const u16* __restrict__ W,
    u16* __restrict__ Cout, int ldc, int K)
{
    __shared__ __align__(16) u16 As[128 * 32];
    __shared__ __align__(16) u16 Ws[128 * 32];

    const int tid  = threadIdx.x;
    const int lane = tid & 63;
    const int wave = tid >> 6;
    const int m0 = blockIdx.y * 128;
    const int n0 = blockIdx.x * 128;

    const int srow = tid >> 2;
    const int scol = (tid & 3) * 8;
    const u16* Arow0 = A + (size_t)(m0 + srow) * lda + scol;
    const u16* Arow1 = A + (size_t)(m0 + 64 + srow) * lda + scol;
    const u16* Wrow0 = W + (size_t)(n0 + srow) * K + scol;
    const u16* Wrow1 = W + (size_t)(n0 + 64 + srow) * K + scol;
    u16* dstA0 = As + wave * 512;
    u16* dstA1 = As + 2048 + wave * 512;
    u16* dstW0 = Ws + wave * 512;
    u16* dstW1 = Ws + 2048 + wave * 512;

    const int wm = (wave >> 1) * 64;
    const int wn = (wave & 1) * 64;
    const int fr = lane & 15;
    const int fq = lane >> 4;

    f32x4 acc[4][4];
    #pragma unroll
    for (int i = 0; i < 4; i++)
        #pragma unroll
        for (int j = 0; j < 4; j++)
            #pragma unroll
            for (int r = 0; r < 4; r++) acc[i][j][r] = 0.0f;

    for (int k0 = 0; k0 < K; k0 += 32) {
        async16(Arow0 + k0, dstA0);
        async16(Arow1 + k0, dstA1);
        async16(Wrow0 + k0, dstW0);
        async16(Wrow1 + k0, dstW1);
        __syncthreads();
        bf16x8 af[4], bw[4];
        #pragma unroll
        for (int i = 0; i < 4; i++)
            af[i] = *(const bf16x8*)&As[(wm + i * 16 + fr) * 32 + fq * 8];
        #pragma unroll
        for (int j = 0; j < 4; j++)
            bw[j] = *(const bf16x8*)&Ws[(wn + j * 16 + fr) * 32 + fq * 8];
        #pragma unroll
        for (int i = 0; i < 4; i++)
            #pragma unroll
            for (int j = 0; j < 4; j++)
                acc[i][j] = __builtin_amdgcn_mfma_f32_16x16x32_bf16(
                    af[i], bw[j], acc[i][j], 0, 0, 0);
        __syncthreads();
    }

    #pragma unroll
    for (int j = 0; j < 4; j++) {
        int col = n0 + wn + j * 16 + fr;
        #pragma unroll
        for (int i = 0; i < 4; i++) {
            int row = m0 + wm + i * 16 + fq * 4;
            #pragma unroll
            for (int r = 0; r < 4; r++)
                Cout[(size_t)(row + r) * ldc + col] = f2bf(acc[i][j][r]);
        }
    }
}

// ---------------------------------------------------------------------------
// gen128: probs = hid[1..32] @ Wgen^T + b_gen.  M=65536 (s-major rows),
// N=128 (97 valid), K=512.  grid (1, 512).  out[b][s][c] scatter on store.
// ---------------------------------------------------------------------------
__global__ __launch_bounds__(256) void gen128(
    const u16* __restrict__ A,        // hid + B*H, rows stride 512
    const u16* __restrict__ Wg,       // [128][512] padded
    const float* __restrict__ bgen,   // [97] fp32
    float* __restrict__ out)
{
    __shared__ __align__(16) u16 As[128 * 32];
    __shared__ __align__(16) u16 Ws[128 * 32];

    const int tid  = threadIdx.x;
    const int lane = tid & 63;
    const int wave = tid >> 6;
    const int m0 = blockIdx.y * 128;

    const int srow = tid >> 2;
    const int scol = (tid & 3) * 8;
    const u16* Arow0 = A + (size_t)(m0 + srow) * HH + scol;
    const u16* Arow1 = A + (size_t)(m0 + 64 + srow) * HH + scol;
    const u16* Wrow0 = Wg + (size_t)srow * HH + scol;
    const u16* Wrow1 = Wg + (size_t)(64 + srow) * HH + scol;
    u16* dstA0 = As + wave * 512;
    u16* dstA1 = As + 2048 + wave * 512;
    u16* dstW0 = Ws + wave * 512;
    u16* dstW1 = Ws + 2048 + wave * 512;

    const int wm = (wave >> 1) * 64;
    const int wn = (wave & 1) * 64;
    const int fr = lane & 15;
    const int fq = lane >> 4;

    f32x4 acc[4][4];
    #pragma unroll
    for (int i = 0; i < 4; i++)
        #pragma unroll
        for (int j = 0; j < 4; j++)
            #pragma unroll
            for (int r = 0; r < 4; r++) acc[i][j][r] = 0.0f;

    for (int k0 = 0; k0 < HH; k0 += 32) {
        async16(Arow0 + k0, dstA0);
        async16(Arow1 + k0, dstA1);
        async16(Wrow0 + k0, dstW0);
        async16(Wrow1 + k0, dstW1);
        __syncthreads();
        bf16x8 af[4], bw[4];
        #pragma unroll
        for (int i = 0; i < 4; i++)
            af[i] = *(const bf16x8*)&As[(wm + i * 16 + fr) * 32 + fq * 8];
        #pragma unroll
        for (int j = 0; j < 4; j++)
            bw[j] = *(const bf16x8*)&Ws[(wn + j * 16 + fr) * 32 + fq * 8];
        #pragma unroll
        for (int i = 0; i < 4; i++)
            #pragma unroll
            for (int j = 0; j < 4; j++)
                acc[i][j] = __builtin_amdgcn_mfma_f32_16x16x32_bf16(
                    af[i], bw[j], acc[i][j], 0, 0, 0);
        __syncthreads();
    }

    #pragma unroll
    for (int j = 0; j < 4; j++) {
        int col = wn + j * 16 + fr;
        if (col < CC) {
            float bv = bgen[col];
            #pragma unroll
            for (int i = 0; i < 4; i++) {
                int row = m0 + wm + i * 16 + fq * 4;
                #pragma unroll
                for (int r = 0; r < 4; r++) {
                    int m = row + r;
                    int s = m >> 11, b = m & (BB - 1);
                    out[(size_t)b * (SS * CC) + s * CC + col] = acc[i][j][r] + bv;
                }
            }
        }
    }
}

// ---------------------------------------------------------------------------
// gates_lstm: gates = [ctx|h_s] @ Wcat^T (interleaved col=4h+g), epilogue adds
// bcat + P[char] and applies LSTM.  Tile 64(M)x128(N), grid (16,32)=512.
// h_{s+1} -> hnext (s-major hid buffer).
// ---------------------------------------------------------------------------
__global__ __launch_bounds__(256) void gates_lstm(
    const u16* __restrict__ ctx,    // [B][512]
    const u16* __restrict__ hprev,  // [B][512] (hid slot s)
    const u16* __restrict__ Wc,     // [2048][1024] interleaved
    const float* __restrict__ bcat, // [2048] interleaved
    const float* __restrict__ P,    // [128][2048] char-gate bias, interleaved
    const int* __restrict__ text,   // [B][SS]
    float* __restrict__ c,          // [B][512]
    u16* __restrict__ hnext,        // [B][512] (hid slot s+1)
    int s)
{
    __shared__ __align__(16) u16 As[64 * 32];    // 4 KB
    __shared__ __align__(16) u16 Ws[128 * 32];   // 8 KB
    __shared__ float gsm[64 * 68];               // 17 KB
    __shared__ int text_sm[64];

    const int tid  = threadIdx.x;
    const int lane = tid & 63;
    const int wave = tid >> 6;

    // XCD swizzle: per-XCD 8x8 region (A 8 strips + W 8 strips < 4 MB L2)
    int b   = blockIdx.y * gridDim.x + blockIdx.x;
    int xcd = b & 7, loc = b >> 3;
    int by = (xcd & 3) * 8 + (loc & 7);     // 0..31  (M tiles)
    int bx = (xcd >> 2) * 8 + (loc >> 3);   // 0..15  (N tiles)
    const int m0 = by * 64;
    const int n0 = bx * 128;

    if (tid < 64) text_sm[tid] = text[(m0 + tid) * SS + s];

    const int srow = tid >> 2;
    const int scol = (tid & 3) * 8;
    const u16* Actx  = ctx   + (size_t)(m0 + srow) * 512 + scol;
    const u16* Ahid  = hprev + (size_t)(m0 + srow) * 512 + scol;
    const u16* Wrow0 = Wc + (size_t)(n0 + srow) * XK2 + scol;
    const u16* Wrow1 = Wc + (size_t)(n0 + 64 + srow) * XK2 + scol;
    u16* dstA  = As + wave * 512;
    u16* dstW0 = Ws + wave * 512;
    u16* dstW1 = Ws + 2048 + wave * 512;

    const int wm = (wave & 1) * 32;   // 2x2 wave grid: 32M x 64N each
    const int wn = (wave >> 1) * 64;
    const int fr = lane & 15;
    const int fq = lane >> 4;

    f32x4 acc[2][4];
    #pragma unroll
    for (int i = 0; i < 2; i++)
        #pragma unroll
        for (int j = 0; j < 4; j++)
            #pragma unroll
            for (int r = 0; r < 4; r++) acc[i][j][r] = 0.0f;

    #pragma unroll
    for (int k0 = 0; k0 < XK2; k0 += 32) {
        const u16* asrc = (k0 < 512) ? (Actx + k0) : (Ahid + (k0 - 512));
        async16(asrc, dstA);
        async16(Wrow0 + k0, dstW0);
        async16(Wrow1 + k0, dstW1);
        __syncthreads();
        bf16x8 af[2], bw[4];
        #pragma unroll
        for (int i = 0; i < 2; i++)
            af[i] = *(const bf16x8*)&As[(wm + i * 16 + fr) * 32 + fq * 8];
        #pragma unroll
        for (int j = 0; j < 4; j++)
            bw[j] = *(const bf16x8*)&Ws[(wn + j * 16 + fr) * 32 + fq * 8];
        #pragma unroll
        for (int i = 0; i < 2; i++)
            #pragma unroll
            for (int j = 0; j < 4; j++)
                acc[i][j] = __builtin_amdgcn_mfma_f32_16x16x32_bf16(
                    af[i], bw[j], acc[i][j], 0, 0, 0);
        __syncthreads();
    }

    // Epilogue: two 64-col passes -> LDS, then fused LSTM (bias+P added here)
    #pragma unroll
    for (int p = 0; p < 2; p++) {
        if ((wave >> 1) == p) {
            #pragma unroll
            for (int j = 0; j < 4; j++) {
                int cl = j * 16 + fr;
                #pragma unroll
                for (int i = 0; i < 2; i++) {
                    int rl = wm + i * 16 + fq * 4;
                    #pragma unroll
                    for (int r = 0; r < 4; r++)
                        gsm[(rl + r) * 68 + cl] = acc[i][j][r];
                }
            }
        }
        __syncthreads();
        #pragma unroll
        for (int rr = 0; rr < 4; rr++) {
            int idx = rr * 256 + tid;
            int u = idx & 15, row = idx >> 4;
            int base = row * 68 + 4 * u;
            int hg = (n0 >> 2) + p * 16 + u;   // global h unit
            int c0 = 4 * hg;                    // interleaved gate col base
            int ch = text_sm[row];
            float4 bc = *(const float4*)(bcat + c0);
            float4 pv = *(const float4*)(P + (size_t)ch * G4 + c0);
            float ig = sig_f(gsm[base]     + bc.x + pv.x);
            float fg = sig_f(gsm[base + 1] + bc.y + pv.y);
            float gg = th_f (gsm[base + 2] + bc.z + pv.z);
            float og = sig_f(gsm[base + 3] + bc.w + pv.w);
            size_t ci = (size_t)(m0 + row) * HH + hg;
            float cn = fg * c[ci] + ig * gg;
            c[ci] = cn;
            hnext[(size_t)(m0 + row) * HH + hg] = f2bf(og * th_f(cn));
        }
        __syncthreads();
    }
}

// ---------------------------------------------------------------------------
// gemm64: 64x64-tile GEMM, fp32 out + bias. Used for ph (N=512,K=512) and the
// one-time P build (N=2048,K=256).
// ---------------------------------------------------------------------------
__global__ __launch_bounds__(256) void gemm64(
    const u16* __restrict__ A, int lda,
    const u16* __restrict__ W, int ldw,
    const float* __restrict__ bias,
    float* __restrict__ Cout, int ldc, int K, int use_bias)
{
    __shared__ __align__(16) u16 As[64][32];
    __shared__ __align__(16) u16 Ws[64][32];

    const int tid  = threadIdx.x;
    const int lane = tid & 63;
    const int wave = tid >> 6;
    const int m0 = blockIdx.y * 64;
    const int n0 = blockIdx.x * 64;
    const int ar = tid >> 2;
    const int ac = (tid & 3) * 8;
    const int wm = (wave >> 1) * 32;
    const int wn = (wave & 1) * 32;
    const int fr = lane & 15;
    const int fq = lane >> 4;

    f32x4 acc[2][2];
    #pragma unroll
    for (int i = 0; i < 2; i++)
        #pragma unroll
        for (int j = 0; j < 2; j++)
            #pragma unroll
            for (int r = 0; r < 4; r++) acc[i][j][r] = 0.0f;

    const u16* Arow = A + (size_t)(m0 + ar) * lda;
    const u16* Wrow = W + (size_t)(n0 + ar) * ldw;

    for (int k0 = 0; k0 < K; k0 += 32) {
        *(uint4*)&As[ar][ac] = *(const uint4*)(Arow + k0 + ac);
        *(uint4*)&Ws[ar][ac] = *(const uint4*)(Wrow + k0 + ac);
        __syncthreads();
        bf16x8 af[2], bw[2];
        #pragma unroll
        for (int mm = 0; mm < 2; mm++)
            af[mm] = *(const bf16x8*)&As[wm + mm * 16 + fr][fq * 8];
        #pragma unroll
        for (int nn = 0; nn < 2; nn++)
            bw[nn] = *(const bf16x8*)&Ws[wn + nn * 16 + fr][fq * 8];
        #pragma unroll
        for (int mm = 0; mm < 2; mm++)
            #pragma unroll
            for (int nn = 0; nn < 2; nn++)
                acc[mm][nn] = __builtin_amdgcn_mfma_f32_16x16x32_bf16(
                    af[mm], bw[nn], acc[mm][nn], 0, 0, 0);
        __syncthreads();
    }

    #pragma unroll
    for (int nn = 0; nn < 2; nn++) {
        int col = n0 + wn + nn * 16 + fr;
        float bv = use_bias ? bias[col] : 0.0f;
        #pragma unroll
        for (int mm = 0; mm < 2; mm++) {
            int row = m0 + wm + mm * 16 + fq * 4;
            #pragma unroll
            for (int r = 0; r < 4; r++)
                Cout[(size_t)(row + r) * ldc + col] = acc[mm][nn][r] + bv;
        }
    }
}

// ---------------------------------------------------------------------------
// attn_step: e/softmax/context into ctx buffer.  1 block / batch row.
// (round-0 structure; softmax wave-parallelized, no tid==0 serial section)
// ---------------------------------------------------------------------------
__global__ __launch_bounds__(256) void attn_step(
    const u16* __restrict__ Hp, const float* __restrict__ ph,
    const float* __restrict__ wscore, const u16* __restrict__ bH16,
    u16* __restrict__ ctx)
{
    const int b = blockIdx.x;
    const int tid = threadIdx.x, lane = tid & 63, wave = tid >> 6;
    __shared__ float e_sm[32];
    __shared__ float alpha_sm[32];

    const int h8 = lane * 8;
    float ph_r[8], ws_r[8];
    {
        float4 p0 = *(const float4*)(ph + (size_t)b * HH + h8);
        float4 p1 = *(const float4*)(ph + (size_t)b * HH + h8 + 4);
        ph_r[0]=p0.x; ph_r[1]=p0.y; ph_r[2]=p0.z; ph_r[3]=p0.w;
        ph_r[4]=p1.x; ph_r[5]=p1.y; ph_r[6]=p1.z; ph_r[7]=p1.w;
        float4 w0 = *(const float4*)(wscore + h8);
        float4 w1 = *(const float4*)(wscore + h8 + 4);
        ws_r[0]=w0.x; ws_r[1]=w0.y; ws_r[2]=w0.z; ws_r[3]=w0.w;
        ws_r[4]=w1.x; ws_r[5]=w1.y; ws_r[6]=w1.z; ws_r[7]=w1.w;
    }

    for (int t = wave; t < TT; t += 4) {
        uint4 hv = *(const uint4*)(Hp + ((size_t)b * TT + t) * HH + h8);
        const u16* hu = (const u16*)&hv;
        float sum = 0.0f;
        #pragma unroll
        for (int j = 0; j < 8; j++)
            sum += th_f(bf2f(hu[j]) + ph_r[j]) * ws_r[j];
        #pragma unroll
        for (int off = 32; off > 0; off >>= 1) sum += __shfl_down(sum, off);
        if (lane == 0) e_sm[t] = sum;
    }
    __syncthreads();

    // wave-parallel softmax over t (wave 0 only; replaces serial tid==0 loop)
    if (wave == 0) {
        float ev = (lane < TT) ? e_sm[lane] : -3.0e38f;
        float mx = ev;
        #pragma unroll
        for (int off = 32; off > 0; off >>= 1)
            mx = fmaxf(mx, __shfl_xor(mx, off));
        float p = (lane < TT) ? __expf(ev - mx) : 0.0f;
        float ssum = p;
        #pragma unroll
        for (int off = 32; off > 0; off >>= 1) ssum += __shfl_xor(ssum, off);
        if (lane < TT) alpha_sm[lane] = p / ssum;
    }
    __syncthreads();

    {
        int d0 = tid * 2;
        float c0 = 0.0f, c1 = 0.0f;
        const u16* bb = bH16 + (size_t)b * TT * DIN + d0;
        #pragma unroll
        for (int t = 0; t < TT; t++) {
            unsigned int v = *(const unsigned int*)(bb + (size_t)t * DIN);
            float a = alpha_sm[t];
            c0 += a * bf2f((u16)(v & 0xffffu));
            c1 += a * bf2f((u16)(v >> 16));
        }
        unsigned int o = (unsigned int)f2bf(c0) | ((unsigned int)f2bf(c1) << 16);
        *(unsigned int*)(ctx + (size_t)b * 512 + d0) = o;
    }
}

// ---------------------------------------------------------------------------
// prep: bH16 cast (separate, big) + prep_all (everything else, one launch)
// ---------------------------------------------------------------------------
__global__ __launch_bounds__(256) void cast_f32_bf16(
    const float* __restrict__ src, u16* __restrict__ dst, int n)
{
    int i = (blockIdx.x * 256 + threadIdx.x) * 4;
    if (i < n) {
        float4 v = *(const float4*)(src + i);
        ushort4 o;
        o.x = f2bf(v.x); o.y = f2bf(v.y); o.z = f2bf(v.z); o.w = f2bf(v.w);
        *(ushort4*)(dst + i) = o;
    }
}

__global__ __launch_bounds__(256) void prep_all(
    const float* __restrict__ W_ih, const float* __restrict__ W_hh,
    const float* __restrict__ b_ih, const float* __restrict__ b_hh,
    const float* __restrict__ b_h2h, const float* __restrict__ emb,
    const float* __restrict__ W_i2h, const float* __restrict__ W_h2h,
    const float* __restrict__ W_gen,
    u16* __restrict__ Wcat, u16* __restrict__ Wce16, u16* __restrict__ emb16,
    u16* __restrict__ Wgen16, u16* __restrict__ Wi2h16, u16* __restrict__ Wh2h16,
    float* __restrict__ bcat, float* __restrict__ cst, u16* __restrict__ hid0,
    float* __restrict__ ph)
{
    int i = blockIdx.x * 256 + threadIdx.x;   // grid covers 2,097,152

    // Wcat [2048][1024] interleaved row np=4h+g: [W_ih[:, :512] | W_hh]
    {
        int np = i >> 10, k = i & (XK2 - 1);
        int h = np >> 2, g = np & 3;
        int n = g * HH + h;
        float v = (k < 512) ? W_ih[(size_t)n * (DIN + EE) + k]
                            : W_hh[(size_t)n * HH + (k - 512)];
        Wcat[(size_t)i] = f2bf(v);
    }
    // Wce16 [2048][256] interleaved: W_ih[:, 512:768]
    if (i < G4 * EE) {
        int np = i >> 8, e = i & (EE - 1);
        int h = np >> 2, g = np & 3;
        int n = g * HH + h;
        Wce16[i] = f2bf(W_ih[(size_t)n * (DIN + EE) + DIN + e]);
    }
    // emb16 [128][256], rows >= 97 zeroed
    if (i < 128 * EE) {
        int ch = i >> 8, e = i & (EE - 1);
        emb16[i] = (ch < CC) ? f2bf(emb[(size_t)ch * EE + e]) : (u16)0;
    }
    // Wgen16 [128][512], rows >= 97 zeroed
    if (i < 128 * HH) {
        int n = i >> 9, k = i & (HH - 1);
        Wgen16[i] = (n < CC) ? f2bf(W_gen[(size_t)n * HH + k]) : (u16)0;
    }
    // Wi2h16, Wh2h16 plain casts
    if (i < HH * DIN) Wi2h16[i] = f2bf(W_i2h[i]);
    if (i < HH * HH)  Wh2h16[i] = f2bf(W_h2h[i]);
    // bcat interleaved
    if (i < G4) {
        int h = i >> 2, g = i & 3;
        int n = g * HH + h;
        bcat[i] = b_ih[n] + b_hh[n];
    }
    // state init: c=0, hid slot0 = 0, ph = b_h2h (h0 = 0)
    if (i < BB * HH) {
        cst[i] = 0.0f;
        hid0[i] = 0;
        ph[i] = b_h2h[i & (HH - 1)];
    }
}

// ---------------------------------------------------------------------------
// Workspace layout (bytes)
// ---------------------------------------------------------------------------
#define BH16_OFF  ((size_t)0)             // bf16 [B*T, DIN]   54,525,952
#define HP_OFF    ((size_t)54525952)      // bf16 [B*T, H]     54,525,952
#define HID_OFF   ((size_t)109051904)     // bf16 [33][B][H]   69,206,016
#define CTX_OFF   ((size_t)178257920)     // bf16 [B][512]      2,097,152
#define WCAT_OFF  ((size_t)180355072)     // bf16 [2048][1024]  4,194,304
#define WCE_OFF   ((size_t)184549376)     // bf16 [2048][256]   1,048,576
#define EMB16_OFF ((size_t)185597952)     // bf16 [128][256]       65,536
#define WGEN_OFF  ((size_t)185663488)     // bf16 [128][512]      131,072
#define WI2H_OFF  ((size_t)185794560)     // bf16 [512][512]      524,288
#define WH2H_OFF  ((size_t)186318848)     // bf16 [512][512]      524,288
#define BCAT_OFF  ((size_t)186843136)     // f32 [2048]             8,192
#define P_OFF     ((size_t)186851328)     // f32 [128][2048]    1,048,576
#define PH_OFF    ((size_t)187899904)     // f32 [B][512]       4,194,304
#define CST_OFF   ((size_t)192094208)     // f32 [B][512]       4,194,304

extern "C" void kernel_launch(void* const* d_in, const int* in_sizes, int n_in,
                              void* d_out, int out_size, void* d_ws, size_t ws_size,
                              hipStream_t stream)
{
    const float* batch_H = (const float*)d_in[0];
    const int*   text    = (const int*)d_in[1];
    const float* W_i2h   = (const float*)d_in[2];
    const float* W_h2h   = (const float*)d_in[3];
    const float* b_h2h   = (const float*)d_in[4];
    const float* w_score = (const float*)d_in[5];
    const float* W_ih    = (const float*)d_in[6];
    const float* W_hh    = (const float*)d_in[7];
    const float* b_ih    = (const float*)d_in[8];
    const float* b_hh    = (const float*)d_in[9];
    const float* W_gen   = (const float*)d_in[10];
    const float* b_gen   = (const float*)d_in[11];
    const float* emb     = (const float*)d_in[12];

    char* ws = (char*)d_ws;
    u16*   bH16   = (u16*)(ws + BH16_OFF);
    u16*   Hp     = (u16*)(ws + HP_OFF);
    u16*   hid    = (u16*)(ws + HID_OFF);
    u16*   ctx    = (u16*)(ws + CTX_OFF);
    u16*   Wcat   = (u16*)(ws + WCAT_OFF);
    u16*   Wce16  = (u16*)(ws + WCE_OFF);
    u16*   emb16  = (u16*)(ws + EMB16_OFF);
    u16*   Wgen16 = (u16*)(ws + WGEN_OFF);
    u16*   Wi2h16 = (u16*)(ws + WI2H_OFF);
    u16*   Wh2h16 = (u16*)(ws + WH2H_OFF);
    float* bcat   = (float*)(ws + BCAT_OFF);
    float* P      = (float*)(ws + P_OFF);
    float* ph     = (float*)(ws + PH_OFF);
    float* cst    = (float*)(ws + CST_OFF);
    float* out    = (float*)d_out;

    // prep (3 launches)
    cast_f32_bf16<<<dim3((BB * TT * DIN / 4 + 255) / 256), 256, 0, stream>>>(
        batch_H, bH16, BB * TT * DIN);
    prep_all<<<dim3((G4 * XK2) / 256), 256, 0, stream>>>(
        W_ih, W_hh, b_ih, b_hh, b_h2h, emb, W_i2h, W_h2h, W_gen,
        Wcat, Wce16, emb16, Wgen16, Wi2h16, Wh2h16, bcat, cst, hid, ph);
    // P[128][2048] = emb16 @ Wce16^T  (fp32 out)
    gemm64<<<dim3(G4 / 64, 128 / 64), 256, 0, stream>>>(
        emb16, EE, Wce16, EE, nullptr, P, G4, EE, 0);

    // Hp = batch_H @ W_i2h^T
    gemm128<<<dim3(HH / 128, (BB * TT) / 128), 256, 0, stream>>>(
        bH16, DIN, Wi2h16, Hp, HH, DIN);

    for (int s = 0; s < SS; s++) {
        u16* hprev = hid + (size_t)s * BB * HH;
        u16* hnext = hid + (size_t)(s + 1) * BB * HH;

        attn_step<<<dim3(BB), 256, 0, stream>>>(Hp, ph, w_score, bH16, ctx);

        gates_lstm<<<dim3(G4 / 128, BB / 64), 256, 0, stream>>>(
            ctx, hprev, Wcat, bcat, P, text, cst, hnext, s);

        // ph = h_{s+1} @ W_h2h^T + b_h2h
        gemm64<<<dim3(HH / 64, BB / 64), 256, 0, stream>>>(
            hnext, HH, Wh2h16, HH, b_h2h, ph, HH, HH, 1);
    }

    // probs = hid[1..32] @ W_gen^T + b_gen  (one big GEMM, scatter store)
    gen128<<<dim3(1, (SS * BB) / 128), 256, 0, stream>>>(
        hid + (size_t)BB * HH, Wgen16, b_gen, out);
}

// Round 3
// 1803.797 us; speedup vs baseline: 1.1324x; 1.0005x over previous
//
#include <hip/hip_runtime.h>

// Problem constants
#define BB 2048
#define TT 26
#define DIN 512
#define HH 512
#define EE 256
#define CC 97
#define SS 32
#define G4 2048   // 4*H
#define XK2 1024  // gates GEMM K: ctx(512) + h(512); ce folded into P lookup
#define NBLK 1024 // persistent grid

typedef unsigned short u16;
typedef __bf16 bf16x8 __attribute__((ext_vector_type(8)));
typedef float f32x4 __attribute__((ext_vector_type(4)));

__device__ __forceinline__ float bf2f(u16 u) {
    return __uint_as_float(((unsigned int)u) << 16);
}
__device__ __forceinline__ u16 f2bf(float f) {  // RNE
    unsigned int u = __float_as_uint(f);
    u = u + 0x7FFFu + ((u >> 16) & 1u);
    return (u16)(u >> 16);
}
__device__ __forceinline__ float th_f(float x) {
    return 1.0f - 2.0f * __builtin_amdgcn_rcpf(__expf(2.0f * x) + 1.0f);
}
__device__ __forceinline__ float sig_f(float x) {
    return __builtin_amdgcn_rcpf(1.0f + __expf(-x));
}

// async global->LDS, 16B/lane; LDS base wave-uniform
__device__ __forceinline__ void async16(const u16* g, u16* l) {
    __builtin_amdgcn_global_load_lds(
        (const __attribute__((address_space(1))) unsigned int*)(g),
        (__attribute__((address_space(3))) unsigned int*)(l), 16, 0, 0);
}

// all-resident grid barrier: leader arrives with agent-scope acq_rel atomic
// (release publishes the block's prior writes after __syncthreads drain);
// trailing __threadfence gives every thread acquire-side cache invalidate.
__device__ __forceinline__ void gridbar(unsigned int* cnt, unsigned int* gen) {
    __syncthreads();
    if (threadIdx.x == 0) {
        unsigned int g = __hip_atomic_load(gen, __ATOMIC_RELAXED, __HIP_MEMORY_SCOPE_AGENT);
        unsigned int v = __hip_atomic_fetch_add(cnt, 1u, __ATOMIC_ACQ_REL, __HIP_MEMORY_SCOPE_AGENT);
        if (v == (unsigned int)(NBLK - 1)) {
            __hip_atomic_store(cnt, 0u, __ATOMIC_RELAXED, __HIP_MEMORY_SCOPE_AGENT);
            __hip_atomic_store(gen, g + 1u, __ATOMIC_RELEASE, __HIP_MEMORY_SCOPE_AGENT);
        } else {
            while (__hip_atomic_load(gen, __ATOMIC_ACQUIRE, __HIP_MEMORY_SCOPE_AGENT) == g)
                __builtin_amdgcn_s_sleep(2);
        }
    }
    __syncthreads();
    __threadfence();
}

// ---------------------------------------------------------------------------
// persist: the whole 32-step recurrence in one kernel.
//   phase 1: ph = hid[s] @ Wh2h^T + b_h2h   (32x32 tile / block)
//   phase 2: attention (2 batch rows / block, 2 waves each)
//   phase 3: gates GEMM + fused LSTM        (64x64 tile / block, c in regs)
// grid 1024 x 256, all blocks co-resident (4/CU), 3 grid barriers / step.
// ---------------------------------------------------------------------------
__global__ __launch_bounds__(256, 4) void persist(
    u16* hid,                  // [33][B][512] bf16
    const u16* __restrict__ Wh,      // Wh2h16 [512][512]
    const float* __restrict__ bh2h,  // [512]
    const u16* __restrict__ Hp,      // [B*T][512]
    const u16* __restrict__ bH16,    // [B*T][512]
    const float* __restrict__ wscore,// [512]
    u16* ctx,                  // [B][512]
    float* phg,                // [B][512] f32
    const u16* __restrict__ Wc,      // [2048][1024] interleaved
    const float* __restrict__ bcat,  // [2048]
    const float* __restrict__ P,     // [128][2048]
    const int* __restrict__ text,    // [B][SS]
    unsigned int* bar)
{
    __shared__ __align__(16) char smem[32768];
    __shared__ float e_sm[2][32];
    __shared__ float alpha_sm[2][32];
    __shared__ int text_sm[64];

    u16* smA = (u16*)smem;             // 16KB
    u16* smB = (u16*)(smem + 16384);   // 16KB
    float* gsm = (float*)smem;         // 64*68 f32 (aliases staging)

    const int tid  = threadIdx.x;
    const int lane = tid & 63;
    const int wave = tid >> 6;
    const int bid  = blockIdx.x;
    const int fr = lane & 15;
    const int fq = lane >> 4;

    unsigned int* bcnt = bar;
    unsigned int* bgen = bar + 32;

    // phase-1 tile: 64 M-tiles x 16 N-tiles of 32x32
    const int p1_m0 = (bid >> 4) * 32;
    const int p1_n0 = (bid & 15) * 32;
    // phase-3 tile: 32 M-tiles x 32 N-tiles of 64x64
    const int p3_m0 = (bid >> 5) * 64;
    const int p3_nt = bid & 31;
    const int p3_n0 = p3_nt * 64;

    // persistent LSTM cell state: item rr <-> (row = (rr*256+tid)>>4, u = (rr*256+tid)&15)
    float c_reg[4] = {0.0f, 0.0f, 0.0f, 0.0f};

    for (int s = 0; s < SS; s++) {
        const u16* hid_s = hid + (size_t)s * BB * HH;
        u16* hid_n = hid + (size_t)(s + 1) * BB * HH;

        // ================= phase 1: ph GEMM (32x32, K=512 in 2 chunks) =====
        {
            f32x4 acc1;
            #pragma unroll
            for (int r = 0; r < 4; r++) acc1[r] = 0.0f;
            const int wm = (wave >> 1) * 16, wn = (wave & 1) * 16;
            #pragma unroll
            for (int cchunk = 0; cchunk < 2; cchunk++) {
                int kc = cchunk * 256;
                #pragma unroll
                for (int j = 0; j < 4; j++) {
                    int row = j * 8 + wave * 2 + (lane >> 5);
                    int col = ((lane & 31) ^ (row & 7)) * 8;   // inverse swizzle on src
                    async16(hid_s + (size_t)(p1_m0 + row) * 512 + kc + col,
                            smA + j * 2048 + wave * 512);
                    async16(Wh + (size_t)(p1_n0 + row) * 512 + kc + col,
                            smB + j * 2048 + wave * 512);
                }
                __syncthreads();
                #pragma unroll
                for (int kk = 0; kk < 8; kk++) {
                    int ra = wm + fr, rb = wn + fr;
                    bf16x8 af = *(const bf16x8*)(smem + ra * 512 +
                                                 (((kk * 4 + fq) ^ (ra & 7)) * 16));
                    bf16x8 bw = *(const bf16x8*)(smem + 16384 + rb * 512 +
                                                 (((kk * 4 + fq) ^ (rb & 7)) * 16));
                    acc1 = __builtin_amdgcn_mfma_f32_16x16x32_bf16(af, bw, acc1, 0, 0, 0);
                }
                __syncthreads();
            }
            int coln = p1_n0 + wn + fr;
            float bv = bh2h[coln];
            #pragma unroll
            for (int r = 0; r < 4; r++)
                phg[(size_t)(p1_m0 + wm + fq * 4 + r) * 512 + coln] = acc1[r] + bv;
        }
        gridbar(bcnt, bgen);

        // ================= phase 2: attention (rows 2*bid, 2*bid+1) ========
        {
            const int rloc = wave >> 1;        // 0,0,1,1
            const int wv = wave & 1;           // wave within row
            const int b = bid * 2 + rloc;
            const int h8 = lane * 8;
            float ph_r[8], ws_r[8];
            {
                float4 p0 = *(const float4*)(phg + (size_t)b * HH + h8);
                float4 p1 = *(const float4*)(phg + (size_t)b * HH + h8 + 4);
                ph_r[0]=p0.x; ph_r[1]=p0.y; ph_r[2]=p0.z; ph_r[3]=p0.w;
                ph_r[4]=p1.x; ph_r[5]=p1.y; ph_r[6]=p1.z; ph_r[7]=p1.w;
                float4 w0 = *(const float4*)(wscore + h8);
                float4 w1 = *(const float4*)(wscore + h8 + 4);
                ws_r[0]=w0.x; ws_r[1]=w0.y; ws_r[2]=w0.z; ws_r[3]=w0.w;
                ws_r[4]=w1.x; ws_r[5]=w1.y; ws_r[6]=w1.z; ws_r[7]=w1.w;
            }
            const u16* hpb = Hp + (size_t)b * TT * 512 + h8;
            for (int t = wv; t < TT; t += 2) {
                uint4 hv = *(const uint4*)(hpb + (size_t)t * 512);
                const u16* hu = (const u16*)&hv;
                float sum = 0.0f;
                #pragma unroll
                for (int j = 0; j < 8; j++)
                    sum += th_f(bf2f(hu[j]) + ph_r[j]) * ws_r[j];
                #pragma unroll
                for (int off = 32; off > 0; off >>= 1) sum += __shfl_down(sum, off);
                if (lane == 0) e_sm[rloc][t] = sum;
            }
            __syncthreads();
            if (wv == 0) {   // waves 0 and 2: softmax for their row
                float ev = (lane < TT) ? e_sm[rloc][lane] : -3.0e38f;
                float mx = ev;
                #pragma unroll
                for (int off = 32; off > 0; off >>= 1)
                    mx = fmaxf(mx, __shfl_xor(mx, off));
                float p = (lane < TT) ? __expf(ev - mx) : 0.0f;
                float ssum = p;
                #pragma unroll
                for (int off = 32; off > 0; off >>= 1) ssum += __shfl_xor(ssum, off);
                if (lane < TT) alpha_sm[rloc][lane] = p / ssum;
            }
            __syncthreads();
            {
                int d0 = (wv * 64 + lane) * 4;
                float ca0 = 0.f, ca1 = 0.f, ca2 = 0.f, ca3 = 0.f;
                const u16* bb = bH16 + (size_t)b * TT * DIN + d0;
                #pragma unroll
                for (int t = 0; t < TT; t++) {
                    uint2 v = *(const uint2*)(bb + (size_t)t * DIN);
                    float a = alpha_sm[rloc][t];
                    ca0 += a * bf2f((u16)(v.x & 0xffffu));
                    ca1 += a * bf2f((u16)(v.x >> 16));
                    ca2 += a * bf2f((u16)(v.y & 0xffffu));
                    ca3 += a * bf2f((u16)(v.y >> 16));
                }
                uint2 o;
                o.x = (unsigned int)f2bf(ca0) | ((unsigned int)f2bf(ca1) << 16);
                o.y = (unsigned int)f2bf(ca2) | ((unsigned int)f2bf(ca3) << 16);
                *(uint2*)(ctx + (size_t)b * 512 + d0) = o;
            }
        }
        gridbar(bcnt, bgen);

        // ================= phase 3: gates GEMM + LSTM (64x64, K=1024) ======
        {
            if (tid < 64) text_sm[tid] = text[(p3_m0 + tid) * SS + s];
            f32x4 acc[2][2];
            #pragma unroll
            for (int i = 0; i < 2; i++)
                #pragma unroll
                for (int j = 0; j < 2; j++)
                    #pragma unroll
                    for (int r = 0; r < 4; r++) acc[i][j][r] = 0.0f;
            const int wm = (wave & 1) * 32, wn = (wave >> 1) * 32;

            for (int chk = 0; chk < 8; chk++) {
                int kc = chk * 128;
                #pragma unroll
                for (int j = 0; j < 4; j++) {
                    int row = j * 16 + wave * 4 + (lane >> 4);
                    int col = ((lane & 15) ^ (row & 7)) * 8;   // inverse swizzle
                    const u16* asrc = (kc < 512)
                        ? (const u16*)(ctx + (size_t)(p3_m0 + row) * 512 + kc + col)
                        : (hid_s + (size_t)(p3_m0 + row) * 512 + (kc - 512) + col);
                    async16(asrc, smA + j * 2048 + wave * 512);
                    async16(Wc + (size_t)(p3_n0 + row) * XK2 + kc + col,
                            smB + j * 2048 + wave * 512);
                }
                __syncthreads();
                #pragma unroll
                for (int kk = 0; kk < 4; kk++) {
                    bf16x8 af[2], bw[2];
                    #pragma unroll
                    for (int i = 0; i < 2; i++) {
                        int ra = wm + i * 16 + fr;
                        af[i] = *(const bf16x8*)(smem + ra * 256 +
                                                 (((kk * 4 + fq) ^ (ra & 7)) * 16));
                    }
                    #pragma unroll
                    for (int j = 0; j < 2; j++) {
                        int rb = wn + j * 16 + fr;
                        bw[j] = *(const bf16x8*)(smem + 16384 + rb * 256 +
                                                 (((kk * 4 + fq) ^ (rb & 7)) * 16));
                    }
                    #pragma unroll
                    for (int i = 0; i < 2; i++)
                        #pragma unroll
                        for (int j = 0; j < 2; j++)
                            acc[i][j] = __builtin_amdgcn_mfma_f32_16x16x32_bf16(
                                af[i], bw[j], acc[i][j], 0, 0, 0);
                }
                __syncthreads();
            }
            // epilogue: acc -> gsm (aliases staging LDS, now dead)
            #pragma unroll
            for (int i = 0; i < 2; i++)
                #pragma unroll
                for (int j = 0; j < 2; j++) {
                    int rl = wm + i * 16 + fq * 4;
                    int cl = wn + j * 16 + fr;
                    #pragma unroll
                    for (int r = 0; r < 4; r++)
                        gsm[(rl + r) * 68 + cl] = acc[i][j][r];
                }
            __syncthreads();
            #pragma unroll
            for (int rr = 0; rr < 4; rr++) {
                int idx = rr * 256 + tid;
                int u = idx & 15, row = idx >> 4;
                int hg = p3_nt * 16 + u;
                int c0 = 4 * hg;
                int chv = text_sm[row];
                float4 bc = *(const float4*)(bcat + c0);
                float4 pv = *(const float4*)(P + (size_t)chv * G4 + c0);
                const float* gb = &gsm[row * 68 + 4 * u];
                float ig = sig_f(gb[0] + bc.x + pv.x);
                float fg = sig_f(gb[1] + bc.y + pv.y);
                float gg = th_f (gb[2] + bc.z + pv.z);
                float og = sig_f(gb[3] + bc.w + pv.w);
                float cn = fg * c_reg[rr] + ig * gg;
                c_reg[rr] = cn;
                hid_n[(size_t)(p3_m0 + row) * HH + hg] = f2bf(og * th_f(cn));
            }
        }
        gridbar(bcnt, bgen);
    }
}

// ---------------------------------------------------------------------------
// gemm128 (Hp): C[M,N] = A[M,K] @ W[N,K]^T, 128x128 tile, m97 staging, bf16 out
// ---------------------------------------------------------------------------
__global__ __launch_bounds__(256) void gemm128(
    const u16* __restrict__ A, int lda,
    const u16* __restrict__ W,
    u16* __restrict__ Cout, int ldc, int K)
{
    __shared__ __align__(16) u16 As[128 * 32];
    __shared__ __align__(16) u16 Ws[128 * 32];

    const int tid  = threadIdx.x;
    const int lane = tid & 63;
    const int wave = tid >> 6;
    const int m0 = blockIdx.y * 128;
    const int n0 = blockIdx.x * 128;

    const int srow = tid >> 2;
    const int scol = (tid & 3) * 8;
    const u16* Arow0 = A + (size_t)(m0 + srow) * lda + scol;
    const u16* Arow1 = A + (size_t)(m0 + 64 + srow) * lda + scol;
    const u16* Wrow0 = W + (size_t)(n0 + srow) * K + scol;
    const u16* Wrow1 = W + (size_t)(n0 + 64 + srow) * K + scol;
    u16* dstA0 = As + wave * 512;
    u16* dstA1 = As + 2048 + wave * 512;
    u16* dstW0 = Ws + wave * 512;
    u16* dstW1 = Ws + 2048 + wave * 512;

    const int wm = (wave >> 1) * 64;
    const int wn = (wave & 1) * 64;
    const int fr = lane & 15;
    const int fq = lane >> 4;

    f32x4 acc[4][4];
    #pragma unroll
    for (int i = 0; i < 4; i++)
        #pragma unroll
        for (int j = 0; j < 4; j++)
            #pragma unroll
            for (int r = 0; r < 4; r++) acc[i][j][r] = 0.0f;

    for (int k0 = 0; k0 < K; k0 += 32) {
        async16(Arow0 + k0, dstA0);
        async16(Arow1 + k0, dstA1);
        async16(Wrow0 + k0, dstW0);
        async16(Wrow1 + k0, dstW1);
        __syncthreads();
        bf16x8 af[4], bw[4];
        #pragma unroll
        for (int i = 0; i < 4; i++)
            af[i] = *(const bf16x8*)&As[(wm + i * 16 + fr) * 32 + fq * 8];
        #pragma unroll
        for (int j = 0; j < 4; j++)
            bw[j] = *(const bf16x8*)&Ws[(wn + j * 16 + fr) * 32 + fq * 8];
        #pragma unroll
        for (int i = 0; i < 4; i++)
            #pragma unroll
            for (int j = 0; j < 4; j++)
                acc[i][j] = __builtin_amdgcn_mfma_f32_16x16x32_bf16(
                    af[i], bw[j], acc[i][j], 0, 0, 0);
        __syncthreads();
    }

    #pragma unroll
    for (int j = 0; j < 4; j++) {
        int col = n0 + wn + j * 16 + fr;
        #pragma unroll
        for (int i = 0; i < 4; i++) {
            int row = m0 + wm + i * 16 + fq * 4;
            #pragma unroll
            for (int r = 0; r < 4; r++)
                Cout[(size_t)(row + r) * ldc + col] = f2bf(acc[i][j][r]);
        }
    }
}

// ---------------------------------------------------------------------------
// gen128: probs = hid[1..32] @ Wgen^T + b_gen.  grid (1, 512).
// ---------------------------------------------------------------------------
__global__ __launch_bounds__(256) void gen128(
    const u16* __restrict__ A,
    const u16* __restrict__ Wg,
    const float* __restrict__ bgen,
    float* __restrict__ out)
{
    __shared__ __align__(16) u16 As[128 * 32];
    __shared__ __align__(16) u16 Ws[128 * 32];

    const int tid  = threadIdx.x;
    const int lane = tid & 63;
    const int wave = tid >> 6;
    const int m0 = blockIdx.y * 128;

    const int srow = tid >> 2;
    const int scol = (tid & 3) * 8;
    const u16* Arow0 = A + (size_t)(m0 + srow) * HH + scol;
    const u16* Arow1 = A + (size_t)(m0 + 64 + srow) * HH + scol;
    const u16* Wrow0 = Wg + (size_t)srow * HH + scol;
    const u16* Wrow1 = Wg + (size_t)(64 + srow) * HH + scol;
    u16* dstA0 = As + wave * 512;
    u16* dstA1 = As + 2048 + wave * 512;
    u16* dstW0 = Ws + wave * 512;
    u16* dstW1 = Ws + 2048 + wave * 512;

    const int wm = (wave >> 1) * 64;
    const int wn = (wave & 1) * 64;
    const int fr = lane & 15;
    const int fq = lane >> 4;

    f32x4 acc[4][4];
    #pragma unroll
    for (int i = 0; i < 4; i++)
        #pragma unroll
        for (int j = 0; j < 4; j++)
            #pragma unroll
            for (int r = 0; r < 4; r++) acc[i][j][r] = 0.0f;

    for (int k0 = 0; k0 < HH; k0 += 32) {
        async16(Arow0 + k0, dstA0);
        async16(Arow1 + k0, dstA1);
        async16(Wrow0 + k0, dstW0);
        async16(Wrow1 + k0, dstW1);
        __syncthreads();
        bf16x8 af[4], bw[4];
        #pragma unroll
        for (int i = 0; i < 4; i++)
            af[i] = *(const bf16x8*)&As[(wm + i * 16 + fr) * 32 + fq * 8];
        #pragma unroll
        for (int j = 0; j < 4; j++)
            bw[j] = *(const bf16x8*)&Ws[(wn + j * 16 + fr) * 32 + fq * 8];
        #pragma unroll
        for (int i = 0; i < 4; i++)
            #pragma unroll
            for (int j = 0; j < 4; j++)
                acc[i][j] = __builtin_amdgcn_mfma_f32_16x16x32_bf16(
                    af[i], bw[j], acc[i][j], 0, 0, 0);
        __syncthreads();
    }

    #pragma unroll
    for (int j = 0; j < 4; j++) {
        int col = wn + j * 16 + fr;
        if (col < CC) {
            float bv = bgen[col];
            #pragma unroll
            for (int i = 0; i < 4; i++) {
                int row = m0 + wm + i * 16 + fq * 4;
                #pragma unroll
                for (int r = 0; r < 4; r++) {
                    int m = row + r;
                    int s = m >> 11, b = m & (BB - 1);
                    out[(size_t)b * (SS * CC) + s * CC + col] = acc[i][j][r] + bv;
                }
            }
        }
    }
}

// ---------------------------------------------------------------------------
// Fallback step kernels (used only if persistent occupancy check fails)
// ---------------------------------------------------------------------------
__global__ __launch_bounds__(256) void gates_lstm(
    const u16* __restrict__ ctx, const u16* __restrict__ hprev,
    const u16* __restrict__ Wc, const float* __restrict__ bcat,
    const float* __restrict__ P, const int* __restrict__ text,
    float* __restrict__ c, u16* __restrict__ hnext, int s)
{
    __shared__ __align__(16) u16 As[64 * 32];
    __shared__ __align__(16) u16 Ws[128 * 32];
    __shared__ float gsm[64 * 68];
    __shared__ int text_sm[64];

    const int tid  = threadIdx.x;
    const int lane = tid & 63;
    const int wave = tid >> 6;

    int b   = blockIdx.y * gridDim.x + blockIdx.x;
    int xcd = b & 7, loc = b >> 3;
    int by = (xcd & 3) * 8 + (loc & 7);
    int bx = (xcd >> 2) * 8 + (loc >> 3);
    const int m0 = by * 64;
    const int n0 = bx * 128;

    if (tid < 64) text_sm[tid] = text[(m0 + tid) * SS + s];

    const int srow = tid >> 2;
    const int scol = (tid & 3) * 8;
    const u16* Actx  = ctx   + (size_t)(m0 + srow) * 512 + scol;
    const u16* Ahid  = hprev + (size_t)(m0 + srow) * 512 + scol;
    const u16* Wrow0 = Wc + (size_t)(n0 + srow) * XK2 + scol;
    const u16* Wrow1 = Wc + (size_t)(n0 + 64 + srow) * XK2 + scol;
    u16* dstA  = As + wave * 512;
    u16* dstW0 = Ws + wave * 512;
    u16* dstW1 = Ws + 2048 + wave * 512;

    const int wm = (wave & 1) * 32;
    const int wn = (wave >> 1) * 64;
    const int fr = lane & 15;
    const int fq = lane >> 4;

    f32x4 acc[2][4];
    #pragma unroll
    for (int i = 0; i < 2; i++)
        #pragma unroll
        for (int j = 0; j < 4; j++)
            #pragma unroll
            for (int r = 0; r < 4; r++) acc[i][j][r] = 0.0f;

    #pragma unroll
    for (int k0 = 0; k0 < XK2; k0 += 32) {
        const u16* asrc = (k0 < 512) ? (Actx + k0) : (Ahid + (k0 - 512));
        async16(asrc, dstA);
        async16(Wrow0 + k0, dstW0);
        async16(Wrow1 + k0, dstW1);
        __syncthreads();
        bf16x8 af[2], bw[4];
        #pragma unroll
        for (int i = 0; i < 2; i++)
            af[i] = *(const bf16x8*)&As[(wm + i * 16 + fr) * 32 + fq * 8];
        #pragma unroll
        for (int j = 0; j < 4; j++)
            bw[j] = *(const bf16x8*)&Ws[(wn + j * 16 + fr) * 32 + fq * 8];
        #pragma unroll
        for (int i = 0; i < 2; i++)
            #pragma unroll
            for (int j = 0; j < 4; j++)
                acc[i][j] = __builtin_amdgcn_mfma_f32_16x16x32_bf16(
                    af[i], bw[j], acc[i][j], 0, 0, 0);
        __syncthreads();
    }

    #pragma unroll
    for (int p = 0; p < 2; p++) {
        if ((wave >> 1) == p) {
            #pragma unroll
            for (int j = 0; j < 4; j++) {
                int cl = j * 16 + fr;
                #pragma unroll
                for (int i = 0; i < 2; i++) {
                    int rl = wm + i * 16 + fq * 4;
                    #pragma unroll
                    for (int r = 0; r < 4; r++)
                        gsm[(rl + r) * 68 + cl] = acc[i][j][r];
                }
            }
        }
        __syncthreads();
        #pragma unroll
        for (int rr = 0; rr < 4; rr++) {
            int idx = rr * 256 + tid;
            int u = idx & 15, row = idx >> 4;
            int base = row * 68 + 4 * u;
            int hg = (n0 >> 2) + p * 16 + u;
            int c0 = 4 * hg;
            int ch = text_sm[row];
            float4 bc = *(const float4*)(bcat + c0);
            float4 pv = *(const float4*)(P + (size_t)ch * G4 + c0);
            float ig = sig_f(gsm[base]     + bc.x + pv.x);
            float fg = sig_f(gsm[base + 1] + bc.y + pv.y);
            float gg = th_f (gsm[base + 2] + bc.z + pv.z);
            float og = sig_f(gsm[base + 3] + bc.w + pv.w);
            size_t ci = (size_t)(m0 + row) * HH + hg;
            float cn = fg * c[ci] + ig * gg;
            c[ci] = cn;
            hnext[(size_t)(m0 + row) * HH + hg] = f2bf(og * th_f(cn));
        }
        __syncthreads();
    }
}

__global__ __launch_bounds__(256) void gemm64(
    const u16* __restrict__ A, int lda,
    const u16* __restrict__ W, int ldw,
    const float* __restrict__ bias,
    float* __restrict__ Cout, int ldc, int K, int use_bias)
{
    __shared__ __align__(16) u16 As[64][32];
    __shared__ __align__(16) u16 Ws[64][32];

    const int tid  = threadIdx.x;
    const int lane = tid & 63;
    const int wave = tid >> 6;
    const int m0 = blockIdx.y * 64;
    const int n0 = blockIdx.x * 64;
    const int ar = tid >> 2;
    const int ac = (tid & 3) * 8;
    const int wm = (wave >> 1) * 32;
    const int wn = (wave & 1) * 32;
    const int fr = lane & 15;
    const int fq = lane >> 4;

    f32x4 acc[2][2];
    #pragma unroll
    for (int i = 0; i < 2; i++)
        #pragma unroll
        for (int j = 0; j < 2; j++)
            #pragma unroll
            for (int r = 0; r < 4; r++) acc[i][j][r] = 0.0f;

    const u16* Arow = A + (size_t)(m0 + ar) * lda;
    const u16* Wrow = W + (size_t)(n0 + ar) * ldw;

    for (int k0 = 0; k0 < K; k0 += 32) {
        *(uint4*)&As[ar][ac] = *(const uint4*)(Arow + k0 + ac);
        *(uint4*)&Ws[ar][ac] = *(const uint4*)(Wrow + k0 + ac);
        __syncthreads();
        bf16x8 af[2], bw[2];
        #pragma unroll
        for (int mm = 0; mm < 2; mm++)
            af[mm] = *(const bf16x8*)&As[wm + mm * 16 + fr][fq * 8];
        #pragma unroll
        for (int nn = 0; nn < 2; nn++)
            bw[nn] = *(const bf16x8*)&Ws[wn + nn * 16 + fr][fq * 8];
        #pragma unroll
        for (int mm = 0; mm < 2; mm++)
            #pragma unroll
            for (int nn = 0; nn < 2; nn++)
                acc[mm][nn] = __builtin_amdgcn_mfma_f32_16x16x32_bf16(
                    af[mm], bw[nn], acc[mm][nn], 0, 0, 0);
        __syncthreads();
    }

    #pragma unroll
    for (int nn = 0; nn < 2; nn++) {
        int col = n0 + wn + nn * 16 + fr;
        float bv = use_bias ? bias[col] : 0.0f;
        #pragma unroll
        for (int mm = 0; mm < 2; mm++) {
            int row = m0 + wm + mm * 16 + fq * 4;
            #pragma unroll
            for (int r = 0; r < 4; r++)
                Cout[(size_t)(row + r) * ldc + col] = acc[mm][nn][r] + bv;
        }
    }
}

__global__ __launch_bounds__(256) void attn_step(
    const u16* __restrict__ Hp, const float* __restrict__ ph,
    const float* __restrict__ wscore, const u16* __restrict__ bH16,
    u16* __restrict__ ctx)
{
    const int b = blockIdx.x;
    const int tid = threadIdx.x, lane = tid & 63, wave = tid >> 6;
    __shared__ float e_sm[32];
    __shared__ float alpha_sm[32];

    const int h8 = lane * 8;
    float ph_r[8], ws_r[8];
    {
        float4 p0 = *(const float4*)(ph + (size_t)b * HH + h8);
        float4 p1 = *(const float4*)(ph + (size_t)b * HH + h8 + 4);
        ph_r[0]=p0.x; ph_r[1]=p0.y; ph_r[2]=p0.z; ph_r[3]=p0.w;
        ph_r[4]=p1.x; ph_r[5]=p1.y; ph_r[6]=p1.z; ph_r[7]=p1.w;
        float4 w0 = *(const float4*)(wscore + h8);
        float4 w1 = *(const float4*)(wscore + h8 + 4);
        ws_r[0]=w0.x; ws_r[1]=w0.y; ws_r[2]=w0.z; ws_r[3]=w0.w;
        ws_r[4]=w1.x; ws_r[5]=w1.y; ws_r[6]=w1.z; ws_r[7]=w1.w;
    }

    for (int t = wave; t < TT; t += 4) {
        uint4 hv = *(const uint4*)(Hp + ((size_t)b * TT + t) * HH + h8);
        const u16* hu = (const u16*)&hv;
        float sum = 0.0f;
        #pragma unroll
        for (int j = 0; j < 8; j++)
            sum += th_f(bf2f(hu[j]) + ph_r[j]) * ws_r[j];
        #pragma unroll
        for (int off = 32; off > 0; off >>= 1) sum += __shfl_down(sum, off);
        if (lane == 0) e_sm[t] = sum;
    }
    __syncthreads();

    if (wave == 0) {
        float ev = (lane < TT) ? e_sm[lane] : -3.0e38f;
        float mx = ev;
        #pragma unroll
        for (int off = 32; off > 0; off >>= 1)
            mx = fmaxf(mx, __shfl_xor(mx, off));
        float p = (lane < TT) ? __expf(ev - mx) : 0.0f;
        float ssum = p;
        #pragma unroll
        for (int off = 32; off > 0; off >>= 1) ssum += __shfl_xor(ssum, off);
        if (lane < TT) alpha_sm[lane] = p / ssum;
    }
    __syncthreads();

    {
        int d0 = tid * 2;
        float c0 = 0.0f, c1 = 0.0f;
        const u16* bb = bH16 + (size_t)b * TT * DIN + d0;
        #pragma unroll
        for (int t = 0; t < TT; t++) {
            unsigned int v = *(const unsigned int*)(bb + (size_t)t * DIN);
            float a = alpha_sm[t];
            c0 += a * bf2f((u16)(v & 0xffffu));
            c1 += a * bf2f((u16)(v >> 16));
        }
        unsigned int o = (unsigned int)f2bf(c0) | ((unsigned int)f2bf(c1) << 16);
        *(unsigned int*)(ctx + (size_t)b * 512 + d0) = o;
    }
}

// ---------------------------------------------------------------------------
// prep
// ---------------------------------------------------------------------------
__global__ __launch_bounds__(256) void cast_f32_bf16(
    const float* __restrict__ src, u16* __restrict__ dst, int n)
{
    int i = (blockIdx.x * 256 + threadIdx.x) * 4;
    if (i < n) {
        float4 v = *(const float4*)(src + i);
        ushort4 o;
        o.x = f2bf(v.x); o.y = f2bf(v.y); o.z = f2bf(v.z); o.w = f2bf(v.w);
        *(ushort4*)(dst + i) = o;
    }
}

__global__ __launch_bounds__(256) void prep_all(
    const float* __restrict__ W_ih, const float* __restrict__ W_hh,
    const float* __restrict__ b_ih, const float* __restrict__ b_hh,
    const float* __restrict__ b_h2h, const float* __restrict__ emb,
    const float* __restrict__ W_i2h, const float* __restrict__ W_h2h,
    const float* __restrict__ W_gen,
    u16* __restrict__ Wcat, u16* __restrict__ Wce16, u16* __restrict__ emb16,
    u16* __restrict__ Wgen16, u16* __restrict__ Wi2h16, u16* __restrict__ Wh2h16,
    float* __restrict__ bcat, float* __restrict__ cst, u16* __restrict__ hid0,
    float* __restrict__ ph, unsigned int* __restrict__ bar)
{
    int i = blockIdx.x * 256 + threadIdx.x;

    {
        int np = i >> 10, k = i & (XK2 - 1);
        int h = np >> 2, g = np & 3;
        int n = g * HH + h;
        float v = (k < 512) ? W_ih[(size_t)n * (DIN + EE) + k]
                            : W_hh[(size_t)n * HH + (k - 512)];
        Wcat[(size_t)i] = f2bf(v);
    }
    if (i < G4 * EE) {
        int np = i >> 8, e = i & (EE - 1);
        int h = np >> 2, g = np & 3;
        int n = g * HH + h;
        Wce16[i] = f2bf(W_ih[(size_t)n * (DIN + EE) + DIN + e]);
    }
    if (i < 128 * EE) {
        int ch = i >> 8, e = i & (EE - 1);
        emb16[i] = (ch < CC) ? f2bf(emb[(size_t)ch * EE + e]) : (u16)0;
    }
    if (i < 128 * HH) {
        int n = i >> 9, k = i & (HH - 1);
        Wgen16[i] = (n < CC) ? f2bf(W_gen[(size_t)n * HH + k]) : (u16)0;
    }
    if (i < HH * DIN) Wi2h16[i] = f2bf(W_i2h[i]);
    if (i < HH * HH)  Wh2h16[i] = f2bf(W_h2h[i]);
    if (i < G4) {
        int h = i >> 2, g = i & 3;
        int n = g * HH + h;
        bcat[i] = b_ih[n] + b_hh[n];
    }
    if (i < BB * HH) {
        cst[i] = 0.0f;
        hid0[i] = 0;
        ph[i] = b_h2h[i & (HH - 1)];
    }
    if (i < 64) bar[i] = 0u;
}

// ---------------------------------------------------------------------------
// Workspace layout (bytes)
// ---------------------------------------------------------------------------
#define BH16_OFF  ((size_t)0)             // bf16 [B*T, DIN]   54,525,952
#define HP_OFF    ((size_t)54525952)      // bf16 [B*T, H]     54,525,952
#define HID_OFF   ((size_t)109051904)     // bf16 [33][B][H]   69,206,016
#define CTX_OFF   ((size_t)178257920)     // bf16 [B][512]      2,097,152
#define WCAT_OFF  ((size_t)180355072)     // bf16 [2048][1024]  4,194,304
#define WCE_OFF   ((size_t)184549376)     // bf16 [2048][256]   1,048,576
#define EMB16_OFF ((size_t)185597952)     // bf16 [128][256]       65,536
#define WGEN_OFF  ((size_t)185663488)     // bf16 [128][512]      131,072
#define WI2H_OFF  ((size_t)185794560)     // bf16 [512][512]      524,288
#define WH2H_OFF  ((size_t)186318848)     // bf16 [512][512]      524,288
#define BCAT_OFF  ((size_t)186843136)     // f32 [2048]             8,192
#define P_OFF     ((size_t)186851328)     // f32 [128][2048]    1,048,576
#define PH_OFF    ((size_t)187899904)     // f32 [B][512]       4,194,304
#define CST_OFF   ((size_t)192094208)     // f32 [B][512]       4,194,304
#define BAR_OFF   ((size_t)196288512)     // u32 [64]                 256

extern "C" void kernel_launch(void* const* d_in, const int* in_sizes, int n_in,
                              void* d_out, int out_size, void* d_ws, size_t ws_size,
                              hipStream_t stream)
{
    const float* batch_H = (const float*)d_in[0];
    const int*   text    = (const int*)d_in[1];
    const float* W_i2h   = (const float*)d_in[2];
    const float* W_h2h   = (const float*)d_in[3];
    const float* b_h2h   = (const float*)d_in[4];
    const float* w_score = (const float*)d_in[5];
    const float* W_ih    = (const float*)d_in[6];
    const float* W_hh    = (const float*)d_in[7];
    const float* b_ih    = (const float*)d_in[8];
    const float* b_hh    = (const float*)d_in[9];
    const float* W_gen   = (const float*)d_in[10];
    const float* b_gen   = (const float*)d_in[11];
    const float* emb     = (const float*)d_in[12];

    char* ws = (char*)d_ws;
    u16*   bH16   = (u16*)(ws + BH16_OFF);
    u16*   Hp     = (u16*)(ws + HP_OFF);
    u16*   hid    = (u16*)(ws + HID_OFF);
    u16*   ctx    = (u16*)(ws + CTX_OFF);
    u16*   Wcat   = (u16*)(ws + WCAT_OFF);
    u16*   Wce16  = (u16*)(ws + WCE_OFF);
    u16*   emb16  = (u16*)(ws + EMB16_OFF);
    u16*   Wgen16 = (u16*)(ws + WGEN_OFF);
    u16*   Wi2h16 = (u16*)(ws + WI2H_OFF);
    u16*   Wh2h16 = (u16*)(ws + WH2H_OFF);
    float* bcat   = (float*)(ws + BCAT_OFF);
    float* P      = (float*)(ws + P_OFF);
    float* ph     = (float*)(ws + PH_OFF);
    float* cst    = (float*)(ws + CST_OFF);
    unsigned int* bar = (unsigned int*)(ws + BAR_OFF);
    float* out    = (float*)d_out;

    // prep (3 launches)
    cast_f32_bf16<<<dim3((BB * TT * DIN / 4 + 255) / 256), 256, 0, stream>>>(
        batch_H, bH16, BB * TT * DIN);
    prep_all<<<dim3((G4 * XK2) / 256), 256, 0, stream>>>(
        W_ih, W_hh, b_ih, b_hh, b_h2h, emb, W_i2h, W_h2h, W_gen,
        Wcat, Wce16, emb16, Wgen16, Wi2h16, Wh2h16, bcat, cst, hid, ph, bar);
    gemm64<<<dim3(G4 / 64, 128 / 64), 256, 0, stream>>>(
        emb16, EE, Wce16, EE, nullptr, P, G4, EE, 0);

    // Hp = batch_H @ W_i2h^T
    gemm128<<<dim3(HH / 128, (BB * TT) / 128), 256, 0, stream>>>(
        bH16, DIN, Wi2h16, Hp, HH, DIN);

    // persistent recurrence if all 1024 blocks can be co-resident
    static int s_occ = -1;
    if (s_occ < 0) {
        int occ = 0;
        if (hipOccupancyMaxActiveBlocksPerMultiprocessor(&occ, persist, 256, 0)
            != hipSuccess) occ = 0;
        s_occ = occ;
    }

    if (s_occ >= 4) {
        persist<<<dim3(NBLK), 256, 0, stream>>>(
            hid, Wh2h16, b_h2h, Hp, bH16, w_score, ctx, ph,
            Wcat, bcat, P, text, bar);
    } else {
        for (int s = 0; s < SS; s++) {
            u16* hprev = hid + (size_t)s * BB * HH;
            u16* hnext = hid + (size_t)(s + 1) * BB * HH;
            attn_step<<<dim3(BB), 256, 0, stream>>>(Hp, ph, w_score, bH16, ctx);
            gates_lstm<<<dim3(G4 / 128, BB / 64), 256, 0, stream>>>(
                ctx, hprev, Wcat, bcat, P, text, cst, hnext, s);
            gemm64<<<dim3(HH / 64, BB / 64), 256, 0, stream>>>(
                hnext, HH, Wh2h16, HH, b_h2h, ph, HH, HH, 1);
        }
    }

    // probs = hid[1..32] @ W_gen^T + b_gen
    gen128<<<dim3(1, (SS * BB) / 128), 256, 0, stream>>>(
        hid + (size_t)BB * HH, Wgen16, b_gen, out);
}